// Round 3
// baseline (939.736 us; speedup 1.0000x reference)
//
#include <hip/hip_runtime.h>
#include <stdint.h>

typedef unsigned short u16;
typedef unsigned int u32;

#define NV 400000
#define KOFF 27
#define EPS_BN 1e-5f

#define INV_ELEMS (KOFF * NV)                 // 10.8M ints
#define INV_BYTES (INV_ELEMS * 4)             // 43.2 MB
#define FEATSBF_OFF INV_BYTES                 // bf16 feats: 51.2 MB
#define WT_OFF (FEATSBF_OFF + NV * 64 * 2)
#define STATS_OFF (WT_OFF + KOFF * 64 * 64 * 2)

using short8 = __attribute__((ext_vector_type(8))) short;
using floatx4 = __attribute__((ext_vector_type(4))) float;

__device__ __forceinline__ u16 f2bf(float f) {
  u32 u = __float_as_uint(f);
  u += 0x7FFFu + ((u >> 16) & 1u);
  return (u16)(u >> 16);
}

// ---------------- prep: inv=-1, stats=0, feats->bf16, W->Wt (transpose+bf16) ----------------
__global__ void k_prep(int* __restrict__ inv, float* __restrict__ stats,
                       const float* __restrict__ feats, u16* __restrict__ featsBf,
                       const float* __restrict__ W, u16* __restrict__ Wt) {
  int i = blockIdx.x * 256 + threadIdx.x;
  if (i < INV_ELEMS / 4) ((int4*)inv)[i] = make_int4(-1, -1, -1, -1);
  if (i < NV * 64 / 4) {
    float4 v = ((const float4*)feats)[i];
    ushort4 o;
    o.x = f2bf(v.x); o.y = f2bf(v.y); o.z = f2bf(v.z); o.w = f2bf(v.w);
    ((ushort4*)featsBf)[i] = o;
  }
  if (i < KOFF * 64 * 64) {
    int k = i >> 12, rem = i & 4095, c = rem >> 6, o = rem & 63;
    Wt[(k << 12) + (o << 6) + c] = f2bf(W[i]);
  }
  if (blockIdx.x == 0) stats[threadIdx.x] = 0.0f;  // sum[64], sq[64]
}

// ---------------- build inverse map: inv[out_idx][k] = in_idx (j-major) ----------------
// within fixed k, valid out_idx are distinct -> no write conflicts
__global__ void k_build(const int* __restrict__ in_idx, const int* __restrict__ out_idx,
                        const float* __restrict__ mask, int* __restrict__ inv) {
  int t = blockIdx.x * 256 + threadIdx.x;
  if (t >= INV_ELEMS) return;
  if (mask[t] != 0.0f) {
    int k = t / NV;
    inv[out_idx[t] * KOFF + k] = in_idx[t];
  }
}

// ---------------- main: barrier-free gather + MFMA, operands direct from global ----------------
__global__ void __launch_bounds__(256, 4)
k_main(const u16* __restrict__ feats, const int* __restrict__ inv,
       const u16* __restrict__ Wt, float* __restrict__ out, float* __restrict__ stats) {
  __shared__ int ibuf[KOFF * 64];      // [k][row]
  __shared__ float redS[4][64];
  __shared__ float redQ[4][64];

  const int t = threadIdx.x;
  const int lane = t & 63;
  const int w = t >> 6;
  const int qm = lane & 15;
  const int quad = lane >> 4;
  const int j0 = blockIdx.x * 64;

  // stage this block's inv rows: global [j][k] (contiguous 1728 ints) -> LDS [k][row]
  const int* g = inv + (long)j0 * KOFF;
#pragma unroll
  for (int i = 0; i < 7; ++i) {
    int e = t + i * 256;
    if (e < KOFF * 64) ibuf[(e % KOFF) * 64 + (e / KOFF)] = g[e];
  }
  __syncthreads();

  floatx4 acc[4];
#pragma unroll
  for (int nt = 0; nt < 4; ++nt) acc[nt] = (floatx4){0.f, 0.f, 0.f, 0.f};

  const int row = w * 16 + qm;         // lane's A row within tile (all quads share)
  int src = ibuf[row];                 // k = 0

#pragma unroll 2
  for (int k = 0; k < KOFF; ++k) {
    int src_next = (k < KOFF - 1) ? ibuf[(k + 1) * 64 + row] : -1;
    // A fragments: 16B each, directly from gathered row; invalid row -> zeros (no traffic)
    short8 a0 = (short8){0, 0, 0, 0, 0, 0, 0, 0};
    short8 a1 = (short8){0, 0, 0, 0, 0, 0, 0, 0};
    if (src >= 0) {
      const u16* ap = feats + (long)src * 64 + quad * 8;
      a0 = *(const short8*)ap;
      a1 = *(const short8*)(ap + 32);
    }
    // B fragments: 16B each from Wt[k] (L1/L2-hot)
    const u16* wk = Wt + (k << 12) + (qm << 6) + quad * 8;
#pragma unroll
    for (int nt = 0; nt < 4; ++nt) {
      short8 b0 = *(const short8*)(wk + nt * 16 * 64);
      short8 b1 = *(const short8*)(wk + nt * 16 * 64 + 32);
      acc[nt] = __builtin_amdgcn_mfma_f32_16x16x32_bf16(a0, b0, acc[nt], 0, 0, 0);
      acc[nt] = __builtin_amdgcn_mfma_f32_16x16x32_bf16(a1, b1, acc[nt], 0, 0, 0);
    }
    src = src_next;
  }

  // epilogue: write pre-BN fp32; D layout: row = quad*4+reg, col = nt*16+qm
#pragma unroll
  for (int nt = 0; nt < 4; ++nt) {
#pragma unroll
    for (int r = 0; r < 4; ++r) {
      int orow = j0 + w * 16 + quad * 4 + r;
      out[(long)orow * 64 + nt * 16 + qm] = acc[nt][r];
    }
  }

  // fused channel stats: lane-col reduce (quad axis spans rows), block reduce, atomic
#pragma unroll
  for (int nt = 0; nt < 4; ++nt) {
    float s = acc[nt][0] + acc[nt][1] + acc[nt][2] + acc[nt][3];
    float q = acc[nt][0] * acc[nt][0] + acc[nt][1] * acc[nt][1] +
              acc[nt][2] * acc[nt][2] + acc[nt][3] * acc[nt][3];
    s += __shfl_xor(s, 16, 64); s += __shfl_xor(s, 32, 64);
    q += __shfl_xor(q, 16, 64); q += __shfl_xor(q, 32, 64);
    if (quad == 0) { redS[w][nt * 16 + qm] = s; redQ[w][nt * 16 + qm] = q; }
  }
  __syncthreads();
  if (t < 64) {
    float s = redS[0][t] + redS[1][t] + redS[2][t] + redS[3][t];
    float q = redQ[0][t] + redQ[1][t] + redQ[2][t] + redQ[3][t];
    atomicAdd(&stats[t], s);
    atomicAdd(&stats[64 + t], q);
  }
}

// ---------------- apply BN + ReLU in place (BN finalize folded in; stats region is hot) ----------------
__global__ void k_apply(float* __restrict__ out, const float* __restrict__ stats,
                        const float* __restrict__ gamma, const float* __restrict__ beta) {
  int i = blockIdx.x * 256 + threadIdx.x;   // one float4 per thread
  if (i >= NV * 64 / 4) return;
  int c0 = (i & 15) * 4;
  float4 v = ((const float4*)out)[i];
  float* pv = (float*)&v;
  const float inv_n = 1.0f / (float)NV;
#pragma unroll
  for (int j = 0; j < 4; ++j) {
    int c = c0 + j;
    float mean = stats[c] * inv_n;
    float var = stats[64 + c] * inv_n - mean * mean;
    float sc = gamma[c] * rsqrtf(var + EPS_BN);
    float y = (pv[j] - mean) * sc + beta[c];
    pv[j] = y > 0.f ? y : 0.f;
  }
  ((float4*)out)[i] = v;
}

extern "C" void kernel_launch(void* const* d_in, const int* in_sizes, int n_in,
                              void* d_out, int out_size, void* d_ws, size_t ws_size,
                              hipStream_t stream) {
  const float* feats = (const float*)d_in[0];
  const float* W     = (const float*)d_in[1];
  const float* gamma = (const float*)d_in[2];
  const float* beta  = (const float*)d_in[3];
  const float* mask  = (const float*)d_in[4];
  const int* in_idx  = (const int*)d_in[5];
  const int* out_idx = (const int*)d_in[6];
  float* out = (float*)d_out;

  char* ws = (char*)d_ws;
  int* inv = (int*)ws;                        // 43.2 MB, layout [j][k]
  u16* featsBf = (u16*)(ws + FEATSBF_OFF);    // 51.2 MB
  u16* Wt = (u16*)(ws + WT_OFF);              // 216 KB, [k][o][c]
  float* stats = (float*)(ws + STATS_OFF);    // 256 floats

  k_prep<<<NV * 64 / 4 / 256, 256, 0, stream>>>(inv, stats, feats, featsBf, W, Wt);
  k_build<<<(INV_ELEMS + 255) / 256, 256, 0, stream>>>(in_idx, out_idx, mask, inv);
  k_main<<<NV / 64, 256, 0, stream>>>(featsBf, inv, Wt, out, stats);
  k_apply<<<NV * 64 / 4 / 256, 256, 0, stream>>>(out, stats, gamma, beta);
}

// Round 4
// 538.449 us; speedup vs baseline: 1.7453x; 1.7453x over previous
//
#include <hip/hip_runtime.h>
#include <stdint.h>

typedef unsigned short u16;
typedef unsigned int u32;

#define NV 400000
#define KOFF 27
#define EPS_BN 1e-5f
#define NROWS 128                             // output rows per block
#define NBLK (NV / NROWS)                     // 3125

#define INV_ELEMS (KOFF * NV)                 // 10.8M ints
#define INV_BYTES (INV_ELEMS * 4)             // 43.2 MB
#define FEATSBF_OFF INV_BYTES                 // bf16 feats: 51.2 MB
#define WT_OFF (FEATSBF_OFF + NV * 64 * 2)
#define STATS_OFF (WT_OFF + KOFF * 64 * 64 * 2)

using short8 = __attribute__((ext_vector_type(8))) short;
using floatx4 = __attribute__((ext_vector_type(4))) float;

__device__ __forceinline__ u16 f2bf(float f) {
  u32 u = __float_as_uint(f);
  u += 0x7FFFu + ((u >> 16) & 1u);
  return (u16)(u >> 16);
}

// ---------------- prep: inv=-1, stats=0, feats->bf16, W->Wt (transpose+bf16) ----------------
__global__ void k_prep(int* __restrict__ inv, float* __restrict__ stats,
                       const float* __restrict__ feats, u16* __restrict__ featsBf,
                       const float* __restrict__ W, u16* __restrict__ Wt) {
  int i = blockIdx.x * 256 + threadIdx.x;
  if (i < INV_ELEMS / 4) ((int4*)inv)[i] = make_int4(-1, -1, -1, -1);
  if (i < NV * 64 / 4) {
    float4 v = ((const float4*)feats)[i];
    ushort4 o;
    o.x = f2bf(v.x); o.y = f2bf(v.y); o.z = f2bf(v.z); o.w = f2bf(v.w);
    ((ushort4*)featsBf)[i] = o;
  }
  if (i < KOFF * 64 * 64) {
    int k = i >> 12, rem = i & 4095, c = rem >> 6, o = rem & 63;
    Wt[(k << 12) + (o << 6) + c] = f2bf(W[i]);
  }
  if (blockIdx.x == 0) stats[threadIdx.x] = 0.0f;  // sum[64], sq[64]
}

// ---------------- build inverse map: inv[k][out_idx] = in_idx ----------------
// within fixed k, out_idx ascending & distinct -> near-sequential writes, no conflicts
__global__ void k_build(const int* __restrict__ in_idx, const int* __restrict__ out_idx,
                        const float* __restrict__ mask, int* __restrict__ inv) {
  int t = blockIdx.x * 256 + threadIdx.x;
  if (t >= INV_ELEMS) return;
  if (mask[t] != 0.0f) {
    int k = t / NV;
    inv[k * NV + out_idx[t]] = in_idx[t];
  }
}

// ---------------- main: bulk-staged gather + dbuf MFMA, 1 barrier per k ----------------
__global__ void __launch_bounds__(256, 2)
k_main(const u16* __restrict__ feats, const int* __restrict__ inv,
       const u16* __restrict__ Wt, float* __restrict__ out, float* __restrict__ stats) {
  __shared__ u16 Asm[2][NROWS][72];    // 72-pitch: 2-way bank alias only (free)
  __shared__ u16 Wsm[2][64][72];
  __shared__ int ibuf[KOFF * NROWS];   // [k][row]
  __shared__ float redS[4][64];
  __shared__ float redQ[4][64];

  const int t = threadIdx.x;
  const int lane = t & 63;
  const int w = t >> 6;
  const int qm = lane & 15;
  const int quad = lane >> 4;
  const int j0 = blockIdx.x * NROWS;

  // preload this block's inv slice: 27 segments of NROWS ints, coalesced
#pragma unroll
  for (int i = 0; i < (KOFF * NROWS + 255) / 256; ++i) {
    int e = t + i * 256;
    if (e < KOFF * NROWS) ibuf[e] = inv[(e >> 7) * NV + j0 + (e & 127)];
  }

  uint4 va[4], vw[2];
  const uint4 zero4 = make_uint4(0, 0, 0, 0);

  // issue gather loads for offset k into registers (no wait)
  auto issue = [&](int k) {
#pragma unroll
    for (int i = 0; i < 4; ++i) {
      int c = t + i * 256;                   // chunk: row=c>>3, seg=c&7
      int src = ibuf[k * NROWS + (c >> 3)];
      uint4 v = zero4;
      if (src >= 0) v = *(const uint4*)(feats + (long)src * 64 + (c & 7) * 8);
      va[i] = v;
    }
    const u16* wk = Wt + (k << 12);
    vw[0] = *(const uint4*)(wk + t * 8);
    vw[1] = *(const uint4*)(wk + (t + 256) * 8);
  };
  // commit staged registers to LDS buffer b
  auto commit = [&](int b) {
#pragma unroll
    for (int i = 0; i < 4; ++i) {
      int c = t + i * 256;
      *(uint4*)&Asm[b][c >> 3][(c & 7) * 8] = va[i];
    }
    *(uint4*)&Wsm[b][t >> 3][(t & 7) * 8] = vw[0];
    int c2 = t + 256;
    *(uint4*)&Wsm[b][c2 >> 3][(c2 & 7) * 8] = vw[1];
  };

  __syncthreads();          // ibuf ready
  issue(0);
  commit(0);
  __syncthreads();          // buf0 ready

  floatx4 acc[2][4];
#pragma unroll
  for (int mt = 0; mt < 2; ++mt)
#pragma unroll
    for (int nt = 0; nt < 4; ++nt) acc[mt][nt] = (floatx4){0.f, 0.f, 0.f, 0.f};

  for (int k = 0; k < KOFF; ++k) {
    int b = k & 1;
    if (k + 1 < KOFF) issue(k + 1);          // loads in flight during MFMAs
    // B fragments once (reused by both m-tiles)
    short8 bf0[4], bf1[4];
#pragma unroll
    for (int nt = 0; nt < 4; ++nt) {
      const u16* bp = &Wsm[b][nt * 16 + qm][quad * 8];
      bf0[nt] = *(const short8*)bp;
      bf1[nt] = *(const short8*)(bp + 32);
    }
#pragma unroll
    for (int mt = 0; mt < 2; ++mt) {
      const u16* ap = &Asm[b][(w + mt * 4) * 16 + qm][quad * 8];
      short8 a0 = *(const short8*)ap;
      short8 a1 = *(const short8*)(ap + 32);
#pragma unroll
      for (int nt = 0; nt < 4; ++nt) {
        acc[mt][nt] = __builtin_amdgcn_mfma_f32_16x16x32_bf16(a0, bf0[nt], acc[mt][nt], 0, 0, 0);
        acc[mt][nt] = __builtin_amdgcn_mfma_f32_16x16x32_bf16(a1, bf1[nt], acc[mt][nt], 0, 0, 0);
      }
    }
    if (k + 1 < KOFF) commit(1 - b);         // waits vmcnt, writes other buffer
    __syncthreads();
  }

  // epilogue: pre-BN fp32; D layout: row = quad*4+reg, col = nt*16+qm
#pragma unroll
  for (int mt = 0; mt < 2; ++mt)
#pragma unroll
    for (int nt = 0; nt < 4; ++nt)
#pragma unroll
      for (int r = 0; r < 4; ++r) {
        int orow = j0 + (w + mt * 4) * 16 + quad * 4 + r;
        out[(long)orow * 64 + nt * 16 + qm] = acc[mt][nt][r];
      }

  // fused channel stats
#pragma unroll
  for (int nt = 0; nt < 4; ++nt) {
    float s = 0.f, q = 0.f;
#pragma unroll
    for (int mt = 0; mt < 2; ++mt)
#pragma unroll
      for (int r = 0; r < 4; ++r) {
        float v = acc[mt][nt][r];
        s += v; q += v * v;
      }
    s += __shfl_xor(s, 16, 64); s += __shfl_xor(s, 32, 64);
    q += __shfl_xor(q, 16, 64); q += __shfl_xor(q, 32, 64);
    if (quad == 0) { redS[w][nt * 16 + qm] = s; redQ[w][nt * 16 + qm] = q; }
  }
  __syncthreads();
  if (t < 64) {
    float s = redS[0][t] + redS[1][t] + redS[2][t] + redS[3][t];
    float q = redQ[0][t] + redQ[1][t] + redQ[2][t] + redQ[3][t];
    atomicAdd(&stats[t], s);
    atomicAdd(&stats[64 + t], q);
  }
}

// ---------------- apply BN + ReLU in place (finalize folded in) ----------------
__global__ void k_apply(float* __restrict__ out, const float* __restrict__ stats,
                        const float* __restrict__ gamma, const float* __restrict__ beta) {
  int i = blockIdx.x * 256 + threadIdx.x;   // one float4 per thread
  if (i >= NV * 64 / 4) return;
  int c0 = (i & 15) * 4;
  float4 v = ((const float4*)out)[i];
  float* pv = (float*)&v;
  const float inv_n = 1.0f / (float)NV;
#pragma unroll
  for (int j = 0; j < 4; ++j) {
    int c = c0 + j;
    float mean = stats[c] * inv_n;
    float var = stats[64 + c] * inv_n - mean * mean;
    float sc = gamma[c] * rsqrtf(var + EPS_BN);
    float y = (pv[j] - mean) * sc + beta[c];
    pv[j] = y > 0.f ? y : 0.f;
  }
  ((float4*)out)[i] = v;
}

extern "C" void kernel_launch(void* const* d_in, const int* in_sizes, int n_in,
                              void* d_out, int out_size, void* d_ws, size_t ws_size,
                              hipStream_t stream) {
  const float* feats = (const float*)d_in[0];
  const float* W     = (const float*)d_in[1];
  const float* gamma = (const float*)d_in[2];
  const float* beta  = (const float*)d_in[3];
  const float* mask  = (const float*)d_in[4];
  const int* in_idx  = (const int*)d_in[5];
  const int* out_idx = (const int*)d_in[6];
  float* out = (float*)d_out;

  char* ws = (char*)d_ws;
  int* inv = (int*)ws;                        // 43.2 MB, layout [k][j]
  u16* featsBf = (u16*)(ws + FEATSBF_OFF);    // 51.2 MB
  u16* Wt = (u16*)(ws + WT_OFF);              // 216 KB, [k][o][c]
  float* stats = (float*)(ws + STATS_OFF);    // 256 floats

  k_prep<<<NV * 64 / 4 / 256, 256, 0, stream>>>(inv, stats, feats, featsBf, W, Wt);
  k_build<<<(INV_ELEMS + 255) / 256, 256, 0, stream>>>(in_idx, out_idx, mask, inv);
  k_main<<<NBLK, 256, 0, stream>>>(featsBf, inv, Wt, out, stats);
  k_apply<<<NV * 64 / 4 / 256, 256, 0, stream>>>(out, stats, gamma, beta);
}